// Round 7
// baseline (4726.049 us; speedup 1.0000x reference)
//
#include <hip/hip_runtime.h>
#include <math.h>

#define NB 32768
#define KC 4096
#define DD 512
#define DELTA 2.0f
#define NGRP 128            // 32-col groups
#define SLOT 8192           // per-group row-list capacity

typedef __attribute__((ext_vector_type(8))) short short8;
typedef __attribute__((ext_vector_type(4))) float facc4;

#define AS1 __attribute__((address_space(1)))
#define AS3 __attribute__((address_space(3)))

__device__ __forceinline__ void gll16(const void* g, void* lds) {
    __builtin_amdgcn_global_load_lds((const AS1 unsigned*)g, (AS3 unsigned*)lds,
                                     16, 0, 0);
}

__device__ __forceinline__ unsigned short f2bf(float f) {
    unsigned u = __float_as_uint(f);
    u += 0x7FFFu + ((u >> 16) & 1u);     // RNE
    return (unsigned short)(u >> 16);
}
__device__ __forceinline__ unsigned ordenc(float f) {
    unsigned u = __float_as_uint(f);
    return (u & 0x80000000u) ? ~u : (u | 0x80000000u);
}

// ---- fp32 -> bf16 convert + tile to [blk][kstep][128 r][64 d], XOR-swizzled ----
__global__ __launch_bounds__(256) void tile_bf16_kernel(const float* __restrict__ in,
                                                        unsigned short* __restrict__ out) {
    const size_t t = (size_t)blockIdx.x * 256 + threadIdx.x;
    const int row = (int)(t >> 6);
    const int d0  = (int)(t & 63) << 3;
    const int blk = row >> 7, r = row & 127;
    const int ks  = d0 >> 6,  dw = d0 & 63;
    const int g   = dw >> 3;
    const int dws = ((g ^ (r & 7)) << 3);
    const float4* p = (const float4*)(in + (size_t)row * DD + d0);
    float4 a = p[0], b = p[1];
    unsigned q0 = (unsigned)f2bf(a.x) | ((unsigned)f2bf(a.y) << 16);
    unsigned q1 = (unsigned)f2bf(a.z) | ((unsigned)f2bf(a.w) << 16);
    unsigned q2 = (unsigned)f2bf(b.x) | ((unsigned)f2bf(b.y) << 16);
    unsigned q3 = (unsigned)f2bf(b.z) | ((unsigned)f2bf(b.w) << 16);
    const size_t o = (((size_t)blk * 8 + ks) * 128 + r) * 64 + dws;
    *(uint4*)(out + o) = make_uint4(q0, q1, q2, q3);
}

// ---------------- c_sq[k] = sum_d c[k][d]^2 (fp32) ----------------
__global__ __launch_bounds__(256) void csq_kernel(const float* __restrict__ cent,
                                                  float* __restrict__ csq) {
    const int wid  = threadIdx.x >> 6;
    const int lane = threadIdx.x & 63;
    const int k = (blockIdx.x << 2) + wid;
    const float* row = cent + (size_t)k * DD;
    float s = 0.f;
#pragma unroll
    for (int d = 0; d < DD; d += 64) {
        float v = row[d + lane];
        s = fmaf(v, v, s);
    }
#pragma unroll
    for (int off = 32; off > 0; off >>= 1) s += __shfl_xor(s, off, 64);
    if (lane == 0) csq[k] = s;
}

// ------ single-pass bf16 MFMA GEMM; locmin[row][128] (32-col groups) ------
__global__ __launch_bounds__(256) void gemm_min(
    const unsigned short* __restrict__ xbT, const unsigned short* __restrict__ cbT,
    const float* __restrict__ csq, float* __restrict__ locmin)
{
    __shared__ unsigned short Ab[8192];   // 16KB
    __shared__ unsigned short Bb[8192];   // 16KB

    const int tid = threadIdx.x;
    const int l = tid & 63, w = tid >> 6;
    const int wr = w >> 1, wc = w & 1;

    const int bid = blockIdx.x;
    const int mblk = bid >> 5, nblk = bid & 31;
    const int m0 = mblk * 128, n0 = nblk * 128;

    const unsigned short* ga = xbT + (size_t)mblk * 8 * 8192 + w * 2048 + l * 8;
    const unsigned short* gb = cbT + (size_t)nblk * 8 * 8192 + w * 2048 + l * 8;

    const int hi = l >> 4, ln = l & 15;

    facc4 acc[4][4];
#pragma unroll
    for (int fr = 0; fr < 4; ++fr)
#pragma unroll
        for (int fc = 0; fc < 4; ++fc) {
            facc4 z = {0.f, 0.f, 0.f, 0.f};
            acc[fr][fc] = z;
        }

#pragma unroll 1
    for (int ks = 0; ks < 8; ++ks) {
        const unsigned short* sa = ga + (size_t)ks * 8192;
        const unsigned short* sb = gb + (size_t)ks * 8192;
#pragma unroll
        for (int q = 0; q < 4; ++q) {
            gll16(sa + q * 512, &Ab[w * 2048 + q * 512]);
            gll16(sb + q * 512, &Bb[w * 2048 + q * 512]);
        }
        __syncthreads();

#pragma unroll
        for (int kk = 0; kk < 2; ++kk) {
            const int ko = ((kk * 4 + hi) ^ (ln & 7)) << 3;
            short8 av[4], bv[4];
#pragma unroll
            for (int fr = 0; fr < 4; ++fr)
                av[fr] = *(const short8*)&Ab[(wr * 64 + fr * 16 + ln) * 64 + ko];
#pragma unroll
            for (int fc = 0; fc < 4; ++fc)
                bv[fc] = *(const short8*)&Bb[(wc * 64 + fc * 16 + ln) * 64 + ko];
#pragma unroll
            for (int fr = 0; fr < 4; ++fr)
#pragma unroll
                for (int fc = 0; fc < 4; ++fc)
                    acc[fr][fc] = __builtin_amdgcn_mfma_f32_16x16x32_bf16(
                        av[fr], bv[fc], acc[fr][fc], 0, 0, 0);
        }
        __syncthreads();
    }

    // epilogue: dist = csq[col] - 2*acc; min per (row, 32-col group half)
    float rm[4][4][2];
#pragma unroll
    for (int fr = 0; fr < 4; ++fr)
#pragma unroll
        for (int j = 0; j < 4; ++j) { rm[fr][j][0] = INFINITY; rm[fr][j][1] = INFINITY; }

#pragma unroll
    for (int fc = 0; fc < 4; ++fc) {
        const int col = n0 + wc * 64 + fc * 16 + ln;
        const float q = csq[col];
#pragma unroll
        for (int fr = 0; fr < 4; ++fr)
#pragma unroll
            for (int j = 0; j < 4; ++j)
                rm[fr][j][fc >> 1] =
                    fminf(rm[fr][j][fc >> 1], fmaf(-2.f, acc[fr][fc][j], q));
    }
#pragma unroll
    for (int off = 1; off < 16; off <<= 1)
#pragma unroll
        for (int fr = 0; fr < 4; ++fr)
#pragma unroll
            for (int j = 0; j < 4; ++j) {
                rm[fr][j][0] = fminf(rm[fr][j][0], __shfl_xor(rm[fr][j][0], off, 64));
                rm[fr][j][1] = fminf(rm[fr][j][1], __shfl_xor(rm[fr][j][1], off, 64));
            }
    if (ln == 0) {
#pragma unroll
        for (int fr = 0; fr < 4; ++fr)
#pragma unroll
            for (int j = 0; j < 4; ++j) {
                const int row = m0 + wr * 64 + fr * 16 + hi * 4 + j;
#pragma unroll
                for (int h = 0; h < 2; ++h)
                    locmin[(size_t)row * NGRP + nblk * 4 + wc * 2 + h] = rm[fr][j][h];
            }
    }
}

// ---- thr[row] = min over 128 group-minima + DELTA (one wave per row) ----
__global__ __launch_bounds__(256) void rowthr_kernel(const float* __restrict__ locmin,
                                                     float* __restrict__ thr) {
    const int row = blockIdx.x * 4 + (threadIdx.x >> 6);
    const int lane = threadIdx.x & 63;
    const float* p = locmin + (size_t)row * NGRP;
    float v = fminf(p[lane], p[64 + lane]);
#pragma unroll
    for (int off = 32; off > 0; off >>= 1) v = fminf(v, __shfl_xor(v, off, 64));
    if (lane == 0) thr[row] = v + DELTA;
}

// ---- qualify: (row,group) with locmin <= thr -> slotted per-group lists ----
__global__ __launch_bounds__(256) void qualify_kernel(
    const float* __restrict__ locmin, const float* __restrict__ thr,
    int* __restrict__ cursor, int* __restrict__ list)
{
    const int row = blockIdx.x * 2 + (threadIdx.x >> 7);
    const int g = threadIdx.x & 127;
    if (locmin[(size_t)row * NGRP + g] <= thr[row]) {
        const int pos = atomicAdd(&cursor[g], 1);
        if (pos < SLOT) list[(size_t)g * SLOT + pos] = row;
    }
}

// ---- rescue: one block per group; exact fp32 dists for 32 cached cols ----
__global__ __launch_bounds__(256) void rescue2_kernel(
    const float* __restrict__ x, const float* __restrict__ cent,
    const float* __restrict__ csq, const int* __restrict__ cursor,
    const int* __restrict__ list, unsigned long long* __restrict__ keys)
{
    const int g = blockIdx.x;
    int n = cursor[g];
    if (n > SLOT) n = SLOT;
    const int l = threadIdx.x & 63, w = threadIdx.x >> 6;
    const int cl = l >> 2, sg = l & 3;   // 16 cols x 4 segs per pass

    for (int i = w; i < n; i += 4) {
        const int row = list[(size_t)g * SLOT + i];
        const float4* xr = (const float4*)(x + (size_t)row * DD + sg * 128);
        unsigned long long best = ~0ull;
#pragma unroll
        for (int pass = 0; pass < 2; ++pass) {
            const int col = g * 32 + pass * 16 + cl;
            const float4* cr = (const float4*)(cent + (size_t)col * DD + sg * 128);
            float s = 0.f;
#pragma unroll
            for (int e = 0; e < 32; ++e) {
                float4 a = xr[e], b = cr[e];
                s = fmaf(a.x, b.x, s);
                s = fmaf(a.y, b.y, s);
                s = fmaf(a.z, b.z, s);
                s = fmaf(a.w, b.w, s);
            }
            s += __shfl_xor(s, 1, 64);
            s += __shfl_xor(s, 2, 64);
            const float dist = fmaf(-2.f, s, csq[col]);
            const unsigned long long key =
                ((unsigned long long)ordenc(dist) << 32) | (unsigned)col;
            best = (key < best) ? key : best;
        }
#pragma unroll
        for (int off = 4; off < 64; off <<= 1) {
            const unsigned long long o = __shfl_xor(best, off, 64);
            best = (o < best) ? o : best;
        }
        if (l == 0) atomicMin(&keys[row], best);
    }
}

__global__ __launch_bounds__(256) void finalize_kernel(
        const unsigned long long* __restrict__ keys, int* __restrict__ out) {
    const int i = blockIdx.x * 256 + threadIdx.x;
    out[i] = (int)(keys[i] & 0xFFFFFFFFull);
}

// ---------------- fallback: round-1 fp32 kernel (proven) ----------------
__global__ __launch_bounds__(256) void argmin_fp32_kernel(
        const float* __restrict__ x, const float* __restrict__ cent,
        const float* __restrict__ csq, int* __restrict__ out) {
    __shared__ float xs[16][68];
    __shared__ float cs[16][132];
    const int tid = threadIdx.x;
    const int tx = tid & 15;
    const int ty = tid >> 4;
    const int m0 = blockIdx.x * 64;
    const int srow = tid >> 2;
    const int scol = (tid & 3) << 2;
    const float* xg  = x + (size_t)(m0 + srow) * DD + scol;
    const float* cgA = cent + (size_t)srow * DD + scol;
    const float* cgB = cent + (size_t)(srow + 64) * DD + scol;
    float best[4];
    int bidx[4];
#pragma unroll
    for (int i = 0; i < 4; ++i) { best[i] = INFINITY; bidx[i] = 0; }
    for (int n0 = 0; n0 < KC; n0 += 128) {
        float acc[4][2][4];
#pragma unroll
        for (int i = 0; i < 4; ++i)
#pragma unroll
            for (int h = 0; h < 2; ++h)
#pragma unroll
                for (int j = 0; j < 4; ++j) acc[i][h][j] = 0.f;
        const size_t nOff = (size_t)n0 * DD;
        float4 rx = *(const float4*)(xg);
        float4 rc0 = *(const float4*)(cgA + nOff);
        float4 rc1 = *(const float4*)(cgB + nOff);
        for (int k0 = 0; k0 < DD; k0 += 16) {
            __syncthreads();
            const float* p = (const float*)&rx;
            xs[scol + 0][srow] = p[0]; xs[scol + 1][srow] = p[1];
            xs[scol + 2][srow] = p[2]; xs[scol + 3][srow] = p[3];
            const float* q0 = (const float*)&rc0;
            cs[scol + 0][srow] = q0[0]; cs[scol + 1][srow] = q0[1];
            cs[scol + 2][srow] = q0[2]; cs[scol + 3][srow] = q0[3];
            const float* q1 = (const float*)&rc1;
            cs[scol + 0][srow + 64] = q1[0]; cs[scol + 1][srow + 64] = q1[1];
            cs[scol + 2][srow + 64] = q1[2]; cs[scol + 3][srow + 64] = q1[3];
            __syncthreads();
            if (k0 + 16 < DD) {
                rx  = *(const float4*)(xg + k0 + 16);
                rc0 = *(const float4*)(cgA + nOff + k0 + 16);
                rc1 = *(const float4*)(cgB + nOff + k0 + 16);
            }
#pragma unroll
            for (int dd = 0; dd < 16; ++dd) {
                float4 av  = *(const float4*)&xs[dd][ty << 2];
                float4 bv0 = *(const float4*)&cs[dd][tx << 2];
                float4 bv1 = *(const float4*)&cs[dd][64 + (tx << 2)];
                const float* a  = (const float*)&av;
                const float* b0 = (const float*)&bv0;
                const float* b1 = (const float*)&bv1;
#pragma unroll
                for (int i = 0; i < 4; ++i)
#pragma unroll
                    for (int j = 0; j < 4; ++j) {
                        acc[i][0][j] = fmaf(a[i], b0[j], acc[i][0][j]);
                        acc[i][1][j] = fmaf(a[i], b1[j], acc[i][1][j]);
                    }
            }
        }
        float4 qv0 = *(const float4*)(csq + n0 + (tx << 2));
        float4 qv1 = *(const float4*)(csq + n0 + 64 + (tx << 2));
        const float* q0 = (const float*)&qv0;
        const float* q1 = (const float*)&qv1;
#pragma unroll
        for (int i = 0; i < 4; ++i)
#pragma unroll
            for (int h = 0; h < 2; ++h)
#pragma unroll
                for (int j = 0; j < 4; ++j) {
                    float qq = (h == 0) ? q0[j] : q1[j];
                    float dist = fmaf(-2.f, acc[i][h][j], qq);
                    int kk = n0 + h * 64 + (tx << 2) + j;
                    if (dist < best[i] || (dist == best[i] && kk < bidx[i])) {
                        best[i] = dist; bidx[i] = kk;
                    }
                }
    }
#pragma unroll
    for (int off = 1; off < 16; off <<= 1)
#pragma unroll
        for (int i = 0; i < 4; ++i) {
            float ov = __shfl_xor(best[i], off, 64);
            int oi = __shfl_xor(bidx[i], off, 64);
            if (ov < best[i] || (ov == best[i] && oi < bidx[i])) {
                best[i] = ov; bidx[i] = oi;
            }
        }
    if (tx == 0)
#pragma unroll
        for (int i = 0; i < 4; ++i) out[m0 + (ty << 2) + i] = bidx[i];
}

extern "C" void kernel_launch(void* const* d_in, const int* in_sizes, int n_in,
                              void* d_out, int out_size, void* d_ws, size_t ws_size,
                              hipStream_t stream) {
    const float* x    = (const float*)d_in[0];
    const float* cent = (const float*)d_in[1];
    int* out = (int*)d_out;

    const size_t xb_bytes     = (size_t)NB * DD * 2;        // 32MB
    const size_t cb_bytes     = (size_t)KC * DD * 2;        // 4MB
    const size_t locmin_bytes = (size_t)NB * NGRP * 4;      // 16MB
    const size_t thr_bytes    = (size_t)NB * 4;             // 128KB
    const size_t keys_bytes   = (size_t)NB * 8;             // 256KB
    const size_t csq_bytes    = (size_t)KC * 4;             // 16KB
    const size_t cur_bytes    = (size_t)NGRP * 4;           // 512B
    const size_t list_bytes   = (size_t)NGRP * SLOT * 4;    // 4MB
    const size_t need = xb_bytes + cb_bytes + locmin_bytes + thr_bytes +
                        keys_bytes + csq_bytes + cur_bytes + list_bytes;

    if (ws_size >= need) {
        char* p = (char*)d_ws;
        unsigned short* xbT = (unsigned short*)p;            p += xb_bytes;
        unsigned short* cbT = (unsigned short*)p;            p += cb_bytes;
        float* locmin = (float*)p;                           p += locmin_bytes;
        float* thr = (float*)p;                              p += thr_bytes;
        unsigned long long* keys = (unsigned long long*)p;   p += keys_bytes;
        float* csq = (float*)p;                              p += csq_bytes;
        int* cursor = (int*)p;                               p += cur_bytes;
        int* list = (int*)p;

        hipMemsetAsync(keys, 0xFF, keys_bytes, stream);
        hipMemsetAsync(cursor, 0, cur_bytes, stream);
        tile_bf16_kernel<<<NB * DD / 8 / 256, 256, 0, stream>>>(x, xbT);
        tile_bf16_kernel<<<KC * DD / 8 / 256, 256, 0, stream>>>(cent, cbT);
        csq_kernel<<<KC / 4, 256, 0, stream>>>(cent, csq);
        gemm_min<<<(NB / 128) * (KC / 128), 256, 0, stream>>>(xbT, cbT, csq, locmin);
        rowthr_kernel<<<NB / 4, 256, 0, stream>>>(locmin, thr);
        qualify_kernel<<<NB / 2, 256, 0, stream>>>(locmin, thr, cursor, list);
        rescue2_kernel<<<NGRP, 256, 0, stream>>>(x, cent, csq, cursor, list, keys);
        finalize_kernel<<<NB / 256, 256, 0, stream>>>(keys, out);
    } else {
        float* csq = (float*)d_ws;
        csq_kernel<<<KC / 4, 256, 0, stream>>>(cent, csq);
        argmin_fp32_kernel<<<NB / 64, 256, 0, stream>>>(x, cent, csq, out);
    }
}

// Round 8
// 1047.138 us; speedup vs baseline: 4.5133x; 4.5133x over previous
//
#include <hip/hip_runtime.h>
#include <math.h>

#define NB 32768
#define KC 4096
#define DD 512
#define DELTA 2.0f
#define NGRP 128                 // 32-col groups
#define PCAP 1048576             // flat pair-list capacity (4MB)

typedef __attribute__((ext_vector_type(8))) short short8;
typedef __attribute__((ext_vector_type(4))) float facc4;

#define AS1 __attribute__((address_space(1)))
#define AS3 __attribute__((address_space(3)))

__device__ __forceinline__ void gll16(const void* g, void* lds) {
    __builtin_amdgcn_global_load_lds((const AS1 unsigned*)g, (AS3 unsigned*)lds,
                                     16, 0, 0);
}

__device__ __forceinline__ unsigned short f2bf(float f) {
    unsigned u = __float_as_uint(f);
    u += 0x7FFFu + ((u >> 16) & 1u);     // RNE
    return (unsigned short)(u >> 16);
}
__device__ __forceinline__ unsigned ordenc(float f) {
    unsigned u = __float_as_uint(f);
    return (u & 0x80000000u) ? ~u : (u | 0x80000000u);
}

// ---- fp32 -> bf16 convert + tile to [blk][kstep][128 r][64 d], XOR-swizzled ----
__global__ __launch_bounds__(256) void tile_bf16_kernel(const float* __restrict__ in,
                                                        unsigned short* __restrict__ out) {
    const size_t t = (size_t)blockIdx.x * 256 + threadIdx.x;
    const int row = (int)(t >> 6);
    const int d0  = (int)(t & 63) << 3;
    const int blk = row >> 7, r = row & 127;
    const int ks  = d0 >> 6,  dw = d0 & 63;
    const int g   = dw >> 3;
    const int dws = ((g ^ (r & 7)) << 3);
    const float4* p = (const float4*)(in + (size_t)row * DD + d0);
    float4 a = p[0], b = p[1];
    unsigned q0 = (unsigned)f2bf(a.x) | ((unsigned)f2bf(a.y) << 16);
    unsigned q1 = (unsigned)f2bf(a.z) | ((unsigned)f2bf(a.w) << 16);
    unsigned q2 = (unsigned)f2bf(b.x) | ((unsigned)f2bf(b.y) << 16);
    unsigned q3 = (unsigned)f2bf(b.z) | ((unsigned)f2bf(b.w) << 16);
    const size_t o = (((size_t)blk * 8 + ks) * 128 + r) * 64 + dws;
    *(uint4*)(out + o) = make_uint4(q0, q1, q2, q3);
}

// ---------------- c_sq[k] = sum_d c[k][d]^2 (fp32) ----------------
__global__ __launch_bounds__(256) void csq_kernel(const float* __restrict__ cent,
                                                  float* __restrict__ csq) {
    const int wid  = threadIdx.x >> 6;
    const int lane = threadIdx.x & 63;
    const int k = (blockIdx.x << 2) + wid;
    const float* row = cent + (size_t)k * DD;
    float s = 0.f;
#pragma unroll
    for (int d = 0; d < DD; d += 64) {
        float v = row[d + lane];
        s = fmaf(v, v, s);
    }
#pragma unroll
    for (int off = 32; off > 0; off >>= 1) s += __shfl_xor(s, off, 64);
    if (lane == 0) csq[k] = s;
}

// ------ single-pass bf16 MFMA GEMM; locmin[row][128] (32-col groups) ------
__global__ __launch_bounds__(256) void gemm_min(
    const unsigned short* __restrict__ xbT, const unsigned short* __restrict__ cbT,
    const float* __restrict__ csq, float* __restrict__ locmin)
{
    __shared__ unsigned short Ab[8192];   // 16KB
    __shared__ unsigned short Bb[8192];   // 16KB

    const int tid = threadIdx.x;
    const int l = tid & 63, w = tid >> 6;
    const int wr = w >> 1, wc = w & 1;

    const int bid = blockIdx.x;
    const int mblk = bid >> 5, nblk = bid & 31;
    const int m0 = mblk * 128, n0 = nblk * 128;

    const unsigned short* ga = xbT + (size_t)mblk * 8 * 8192 + w * 2048 + l * 8;
    const unsigned short* gb = cbT + (size_t)nblk * 8 * 8192 + w * 2048 + l * 8;

    const int hi = l >> 4, ln = l & 15;

    facc4 acc[4][4];
#pragma unroll
    for (int fr = 0; fr < 4; ++fr)
#pragma unroll
        for (int fc = 0; fc < 4; ++fc) {
            facc4 z = {0.f, 0.f, 0.f, 0.f};
            acc[fr][fc] = z;
        }

#pragma unroll 1
    for (int ks = 0; ks < 8; ++ks) {
        const unsigned short* sa = ga + (size_t)ks * 8192;
        const unsigned short* sb = gb + (size_t)ks * 8192;
#pragma unroll
        for (int q = 0; q < 4; ++q) {
            gll16(sa + q * 512, &Ab[w * 2048 + q * 512]);
            gll16(sb + q * 512, &Bb[w * 2048 + q * 512]);
        }
        __syncthreads();

#pragma unroll
        for (int kk = 0; kk < 2; ++kk) {
            const int ko = ((kk * 4 + hi) ^ (ln & 7)) << 3;
            short8 av[4], bv[4];
#pragma unroll
            for (int fr = 0; fr < 4; ++fr)
                av[fr] = *(const short8*)&Ab[(wr * 64 + fr * 16 + ln) * 64 + ko];
#pragma unroll
            for (int fc = 0; fc < 4; ++fc)
                bv[fc] = *(const short8*)&Bb[(wc * 64 + fc * 16 + ln) * 64 + ko];
#pragma unroll
            for (int fr = 0; fr < 4; ++fr)
#pragma unroll
                for (int fc = 0; fc < 4; ++fc)
                    acc[fr][fc] = __builtin_amdgcn_mfma_f32_16x16x32_bf16(
                        av[fr], bv[fc], acc[fr][fc], 0, 0, 0);
        }
        __syncthreads();
    }

    float rm[4][4][2];
#pragma unroll
    for (int fr = 0; fr < 4; ++fr)
#pragma unroll
        for (int j = 0; j < 4; ++j) { rm[fr][j][0] = INFINITY; rm[fr][j][1] = INFINITY; }

#pragma unroll
    for (int fc = 0; fc < 4; ++fc) {
        const int col = n0 + wc * 64 + fc * 16 + ln;
        const float q = csq[col];
#pragma unroll
        for (int fr = 0; fr < 4; ++fr)
#pragma unroll
            for (int j = 0; j < 4; ++j)
                rm[fr][j][fc >> 1] =
                    fminf(rm[fr][j][fc >> 1], fmaf(-2.f, acc[fr][fc][j], q));
    }
#pragma unroll
    for (int off = 1; off < 16; off <<= 1)
#pragma unroll
        for (int fr = 0; fr < 4; ++fr)
#pragma unroll
            for (int j = 0; j < 4; ++j) {
                rm[fr][j][0] = fminf(rm[fr][j][0], __shfl_xor(rm[fr][j][0], off, 64));
                rm[fr][j][1] = fminf(rm[fr][j][1], __shfl_xor(rm[fr][j][1], off, 64));
            }
    if (ln == 0) {
#pragma unroll
        for (int fr = 0; fr < 4; ++fr)
#pragma unroll
            for (int j = 0; j < 4; ++j) {
                const int row = m0 + wr * 64 + fr * 16 + hi * 4 + j;
#pragma unroll
                for (int h = 0; h < 2; ++h)
                    locmin[(size_t)row * NGRP + nblk * 4 + wc * 2 + h] = rm[fr][j][h];
            }
    }
}

// ---- thr[row] = min over 128 group-minima + DELTA (one wave per row) ----
__global__ __launch_bounds__(256) void rowthr_kernel(const float* __restrict__ locmin,
                                                     float* __restrict__ thr) {
    const int row = blockIdx.x * 4 + (threadIdx.x >> 6);
    const int lane = threadIdx.x & 63;
    const float* p = locmin + (size_t)row * NGRP;
    float v = fminf(p[lane], p[64 + lane]);
#pragma unroll
    for (int off = 32; off > 0; off >>= 1) v = fminf(v, __shfl_xor(v, off, 64));
    if (lane == 0) thr[row] = v + DELTA;
}

// ---- qualify: (row,g) with locmin <= thr -> flat packed pair list ----
__global__ __launch_bounds__(256) void qualify_kernel(
    const float* __restrict__ locmin, const float* __restrict__ thr,
    const float* __restrict__ x, const float* __restrict__ cent,
    const float* __restrict__ csq,
    int* __restrict__ counter, int* __restrict__ list,
    unsigned long long* __restrict__ keys)
{
    const int row = blockIdx.x * 2 + (threadIdx.x >> 7);
    const int g = threadIdx.x & 127;
    if (locmin[(size_t)row * NGRP + g] <= thr[row]) {
        const int pos = atomicAdd(counter, 1);
        if (pos < PCAP) {
            list[pos] = (row << 7) | g;
        } else {
            // overflow fallback (statistically dead): exact inline rescue
            unsigned long long best = ~0ull;
            for (int c = 0; c < 32; ++c) {
                const int col = g * 32 + c;
                const float* xr = x + (size_t)row * DD;
                const float* cr = cent + (size_t)col * DD;
                float s = 0.f;
                for (int d = 0; d < DD; ++d) s = fmaf(xr[d], cr[d], s);
                const float dist = fmaf(-2.f, s, csq[col]);
                const unsigned long long key =
                    ((unsigned long long)ordenc(dist) << 32) | (unsigned)col;
                best = (key < best) ? key : best;
            }
            atomicMin(&keys[row], best);
        }
    }
}

// ---- rescue: grid-stride waves over flat pairs; 1 pair per wave-iter ----
// lane layout: cl = l>>1 (32 cols), sg = l&1 (2 halves of 256 dims)
__global__ __launch_bounds__(256) void rescue_flat_kernel(
    const float* __restrict__ x, const float* __restrict__ cent,
    const float* __restrict__ csq, const int* __restrict__ counter,
    const int* __restrict__ list, unsigned long long* __restrict__ keys)
{
    int npairs = *counter;
    if (npairs > PCAP) npairs = PCAP;
    const int nwaves = gridDim.x * 4;
    const int wid = blockIdx.x * 4 + (threadIdx.x >> 6);
    const int l = threadIdx.x & 63;
    const int cl = l >> 1, sg = l & 1;

    for (int p = wid; p < npairs; p += nwaves) {
        const int pair = list[p];
        const int row = pair >> 7, g = pair & 127;
        const int col = g * 32 + cl;
        const float4* xr = (const float4*)(x + (size_t)row * DD + sg * 256);
        const float4* cr = (const float4*)(cent + (size_t)col * DD + sg * 256);
        float s0 = 0.f, s1 = 0.f, s2 = 0.f, s3 = 0.f;
#pragma unroll 8
        for (int e = 0; e < 64; ++e) {
            const float4 a = xr[e], b = cr[e];
            s0 = fmaf(a.x, b.x, s0);
            s1 = fmaf(a.y, b.y, s1);
            s2 = fmaf(a.z, b.z, s2);
            s3 = fmaf(a.w, b.w, s3);
        }
        float s = (s0 + s1) + (s2 + s3);
        s += __shfl_xor(s, 1, 64);                 // combine the two halves
        const float dist = fmaf(-2.f, s, csq[col]);
        unsigned long long best =
            ((unsigned long long)ordenc(dist) << 32) | (unsigned)col;
#pragma unroll
        for (int off = 2; off < 64; off <<= 1) {
            const unsigned long long o = __shfl_xor(best, off, 64);
            best = (o < best) ? o : best;
        }
        if (l == 0) atomicMin(&keys[row], best);
    }
}

__global__ __launch_bounds__(256) void finalize_kernel(
        const unsigned long long* __restrict__ keys, int* __restrict__ out) {
    const int i = blockIdx.x * 256 + threadIdx.x;
    out[i] = (int)(keys[i] & 0xFFFFFFFFull);
}

// ---------------- fallback: round-1 fp32 kernel (proven) ----------------
__global__ __launch_bounds__(256) void argmin_fp32_kernel(
        const float* __restrict__ x, const float* __restrict__ cent,
        const float* __restrict__ csq, int* __restrict__ out) {
    __shared__ float xs[16][68];
    __shared__ float cs[16][132];
    const int tid = threadIdx.x;
    const int tx = tid & 15;
    const int ty = tid >> 4;
    const int m0 = blockIdx.x * 64;
    const int srow = tid >> 2;
    const int scol = (tid & 3) << 2;
    const float* xg  = x + (size_t)(m0 + srow) * DD + scol;
    const float* cgA = cent + (size_t)srow * DD + scol;
    const float* cgB = cent + (size_t)(srow + 64) * DD + scol;
    float best[4];
    int bidx[4];
#pragma unroll
    for (int i = 0; i < 4; ++i) { best[i] = INFINITY; bidx[i] = 0; }
    for (int n0 = 0; n0 < KC; n0 += 128) {
        float acc[4][2][4];
#pragma unroll
        for (int i = 0; i < 4; ++i)
#pragma unroll
            for (int h = 0; h < 2; ++h)
#pragma unroll
                for (int j = 0; j < 4; ++j) acc[i][h][j] = 0.f;
        const size_t nOff = (size_t)n0 * DD;
        float4 rx = *(const float4*)(xg);
        float4 rc0 = *(const float4*)(cgA + nOff);
        float4 rc1 = *(const float4*)(cgB + nOff);
        for (int k0 = 0; k0 < DD; k0 += 16) {
            __syncthreads();
            const float* p = (const float*)&rx;
            xs[scol + 0][srow] = p[0]; xs[scol + 1][srow] = p[1];
            xs[scol + 2][srow] = p[2]; xs[scol + 3][srow] = p[3];
            const float* q0 = (const float*)&rc0;
            cs[scol + 0][srow] = q0[0]; cs[scol + 1][srow] = q0[1];
            cs[scol + 2][srow] = q0[2]; cs[scol + 3][srow] = q0[3];
            const float* q1 = (const float*)&rc1;
            cs[scol + 0][srow + 64] = q1[0]; cs[scol + 1][srow + 64] = q1[1];
            cs[scol + 2][srow + 64] = q1[2]; cs[scol + 3][srow + 64] = q1[3];
            __syncthreads();
            if (k0 + 16 < DD) {
                rx  = *(const float4*)(xg + k0 + 16);
                rc0 = *(const float4*)(cgA + nOff + k0 + 16);
                rc1 = *(const float4*)(cgB + nOff + k0 + 16);
            }
#pragma unroll
            for (int dd = 0; dd < 16; ++dd) {
                float4 av  = *(const float4*)&xs[dd][ty << 2];
                float4 bv0 = *(const float4*)&cs[dd][tx << 2];
                float4 bv1 = *(const float4*)&cs[dd][64 + (tx << 2)];
                const float* a  = (const float*)&av;
                const float* b0 = (const float*)&bv0;
                const float* b1 = (const float*)&bv1;
#pragma unroll
                for (int i = 0; i < 4; ++i)
#pragma unroll
                    for (int j = 0; j < 4; ++j) {
                        acc[i][0][j] = fmaf(a[i], b0[j], acc[i][0][j]);
                        acc[i][1][j] = fmaf(a[i], b1[j], acc[i][1][j]);
                    }
            }
        }
        float4 qv0 = *(const float4*)(csq + n0 + (tx << 2));
        float4 qv1 = *(const float4*)(csq + n0 + 64 + (tx << 2));
        const float* q0 = (const float*)&qv0;
        const float* q1 = (const float*)&qv1;
#pragma unroll
        for (int i = 0; i < 4; ++i)
#pragma unroll
            for (int h = 0; h < 2; ++h)
#pragma unroll
                for (int j = 0; j < 4; ++j) {
                    float qq = (h == 0) ? q0[j] : q1[j];
                    float dist = fmaf(-2.f, acc[i][h][j], qq);
                    int kk = n0 + h * 64 + (tx << 2) + j;
                    if (dist < best[i] || (dist == best[i] && kk < bidx[i])) {
                        best[i] = dist; bidx[i] = kk;
                    }
                }
    }
#pragma unroll
    for (int off = 1; off < 16; off <<= 1)
#pragma unroll
        for (int i = 0; i < 4; ++i) {
            float ov = __shfl_xor(best[i], off, 64);
            int oi = __shfl_xor(bidx[i], off, 64);
            if (ov < best[i] || (ov == best[i] && oi < bidx[i])) {
                best[i] = ov; bidx[i] = oi;
            }
        }
    if (tx == 0)
#pragma unroll
        for (int i = 0; i < 4; ++i) out[m0 + (ty << 2) + i] = bidx[i];
}

extern "C" void kernel_launch(void* const* d_in, const int* in_sizes, int n_in,
                              void* d_out, int out_size, void* d_ws, size_t ws_size,
                              hipStream_t stream) {
    const float* x    = (const float*)d_in[0];
    const float* cent = (const float*)d_in[1];
    int* out = (int*)d_out;

    const size_t xb_bytes     = (size_t)NB * DD * 2;        // 32MB
    const size_t cb_bytes     = (size_t)KC * DD * 2;        // 4MB
    const size_t locmin_bytes = (size_t)NB * NGRP * 4;      // 16MB
    const size_t thr_bytes    = (size_t)NB * 4;             // 128KB
    const size_t keys_bytes   = (size_t)NB * 8;             // 256KB
    const size_t csq_bytes    = (size_t)KC * 4;             // 16KB
    const size_t cnt_bytes    = 512;
    const size_t list_bytes   = (size_t)PCAP * 4;           // 4MB
    const size_t need = xb_bytes + cb_bytes + locmin_bytes + thr_bytes +
                        keys_bytes + csq_bytes + cnt_bytes + list_bytes;

    if (ws_size >= need) {
        char* p = (char*)d_ws;
        unsigned short* xbT = (unsigned short*)p;            p += xb_bytes;
        unsigned short* cbT = (unsigned short*)p;            p += cb_bytes;
        float* locmin = (float*)p;                           p += locmin_bytes;
        float* thr = (float*)p;                              p += thr_bytes;
        unsigned long long* keys = (unsigned long long*)p;   p += keys_bytes;
        float* csq = (float*)p;                              p += csq_bytes;
        int* counter = (int*)p;                              p += cnt_bytes;
        int* list = (int*)p;

        hipMemsetAsync(keys, 0xFF, keys_bytes, stream);
        hipMemsetAsync(counter, 0, cnt_bytes, stream);
        tile_bf16_kernel<<<NB * DD / 8 / 256, 256, 0, stream>>>(x, xbT);
        tile_bf16_kernel<<<KC * DD / 8 / 256, 256, 0, stream>>>(cent, cbT);
        csq_kernel<<<KC / 4, 256, 0, stream>>>(cent, csq);
        gemm_min<<<(NB / 128) * (KC / 128), 256, 0, stream>>>(xbT, cbT, csq, locmin);
        rowthr_kernel<<<NB / 4, 256, 0, stream>>>(locmin, thr);
        qualify_kernel<<<NB / 2, 256, 0, stream>>>(locmin, thr, x, cent, csq,
                                                   counter, list, keys);
        rescue_flat_kernel<<<2048, 256, 0, stream>>>(x, cent, csq, counter, list, keys);
        finalize_kernel<<<NB / 256, 256, 0, stream>>>(keys, out);
    } else {
        float* csq = (float*)d_ws;
        csq_kernel<<<KC / 4, 256, 0, stream>>>(cent, csq);
        argmin_fp32_kernel<<<NB / 64, 256, 0, stream>>>(x, cent, csq, out);
    }
}

// Round 9
// 653.486 us; speedup vs baseline: 7.2321x; 1.6024x over previous
//
#include <hip/hip_runtime.h>
#include <math.h>

#define NB 32768
#define KC 4096
#define DD 512
#define DELTA 2.0f
#define PCAP 1048576             // flat pair-list capacity (4MB)

typedef __attribute__((ext_vector_type(8))) short short8;
typedef __attribute__((ext_vector_type(4))) float facc4;

#define AS1 __attribute__((address_space(1)))
#define AS3 __attribute__((address_space(3)))

__device__ __forceinline__ void gll16(const void* g, void* lds) {
    __builtin_amdgcn_global_load_lds((const AS1 unsigned*)g, (AS3 unsigned*)lds,
                                     16, 0, 0);
}

__device__ __forceinline__ unsigned short f2bf(float f) {
    unsigned u = __float_as_uint(f);
    u += 0x7FFFu + ((u >> 16) & 1u);     // RNE
    return (unsigned short)(u >> 16);
}
__device__ __forceinline__ unsigned ordenc(float f) {
    unsigned u = __float_as_uint(f);
    return (u & 0x80000000u) ? ~u : (u | 0x80000000u);
}
__device__ __forceinline__ float orddec(unsigned o) {
    unsigned u = (o & 0x80000000u) ? (o & 0x7FFFFFFFu) : ~o;
    return __uint_as_float(u);
}
// bf16 rounded toward -inf (conservative lower bound of f)
__device__ __forceinline__ unsigned bf16dn(float f) {
    unsigned u = __float_as_uint(f);
    unsigned t = u >> 16;
    if ((u & 0xFFFFu) && (u >> 31)) t += 1;   // negative: away from zero
    return t & 0xFFFFu;
}
__device__ __forceinline__ float bf16dec(unsigned t) {
    return __uint_as_float(t << 16);
}

// ---- fp32 -> bf16 convert + tile to [blk][kstep][128 r][64 d], XOR-swizzled ----
__global__ __launch_bounds__(256) void tile_bf16_kernel(const float* __restrict__ in,
                                                        unsigned short* __restrict__ out) {
    const size_t t = (size_t)blockIdx.x * 256 + threadIdx.x;
    const int row = (int)(t >> 6);
    const int d0  = (int)(t & 63) << 3;
    const int blk = row >> 7, r = row & 127;
    const int ks  = d0 >> 6,  dw = d0 & 63;
    const int g   = dw >> 3;
    const int dws = ((g ^ (r & 7)) << 3);
    const float4* p = (const float4*)(in + (size_t)row * DD + d0);
    float4 a = p[0], b = p[1];
    unsigned q0 = (unsigned)f2bf(a.x) | ((unsigned)f2bf(a.y) << 16);
    unsigned q1 = (unsigned)f2bf(a.z) | ((unsigned)f2bf(a.w) << 16);
    unsigned q2 = (unsigned)f2bf(b.x) | ((unsigned)f2bf(b.y) << 16);
    unsigned q3 = (unsigned)f2bf(b.z) | ((unsigned)f2bf(b.w) << 16);
    const size_t o = (((size_t)blk * 8 + ks) * 128 + r) * 64 + dws;
    *(uint4*)(out + o) = make_uint4(q0, q1, q2, q3);
}

// ---------------- c_sq[k] = sum_d c[k][d]^2 (fp32) ----------------
__global__ __launch_bounds__(256) void csq_kernel(const float* __restrict__ cent,
                                                  float* __restrict__ csq) {
    const int wid  = threadIdx.x >> 6;
    const int lane = threadIdx.x & 63;
    const int k = (blockIdx.x << 2) + wid;
    const float* row = cent + (size_t)k * DD;
    float s = 0.f;
#pragma unroll
    for (int d = 0; d < DD; d += 64) {
        float v = row[d + lane];
        s = fmaf(v, v, s);
    }
#pragma unroll
    for (int off = 32; off > 0; off >>= 1) s += __shfl_xor(s, off, 64);
    if (lane == 0) csq[k] = s;
}

// ------ single-pass bf16 MFMA GEMM; locmin64[row][64]: per-64-col-group ------
// u64 = { ordenc(min):32 | bf16_down(min2):16 | pad | argmin_in_group:6 }
__global__ __launch_bounds__(256) void gemm_min(
    const unsigned short* __restrict__ xbT, const unsigned short* __restrict__ cbT,
    const float* __restrict__ csq, unsigned long long* __restrict__ locmin64)
{
    __shared__ unsigned short Ab[8192];   // 16KB
    __shared__ unsigned short Bb[8192];   // 16KB

    const int tid = threadIdx.x;
    const int l = tid & 63, w = tid >> 6;
    const int wr = w >> 1, wc = w & 1;

    const int bid = blockIdx.x;
    const int mblk = bid >> 5, nblk = bid & 31;
    const int m0 = mblk * 128, n0 = nblk * 128;

    const unsigned short* ga = xbT + (size_t)mblk * 8 * 8192 + w * 2048 + l * 8;
    const unsigned short* gb = cbT + (size_t)nblk * 8 * 8192 + w * 2048 + l * 8;

    const int hi = l >> 4, ln = l & 15;

    facc4 acc[4][4];
#pragma unroll
    for (int fr = 0; fr < 4; ++fr)
#pragma unroll
        for (int fc = 0; fc < 4; ++fc) {
            facc4 z = {0.f, 0.f, 0.f, 0.f};
            acc[fr][fc] = z;
        }

#pragma unroll 1
    for (int ks = 0; ks < 8; ++ks) {
        const unsigned short* sa = ga + (size_t)ks * 8192;
        const unsigned short* sb = gb + (size_t)ks * 8192;
#pragma unroll
        for (int q = 0; q < 4; ++q) {
            gll16(sa + q * 512, &Ab[w * 2048 + q * 512]);
            gll16(sb + q * 512, &Bb[w * 2048 + q * 512]);
        }
        __syncthreads();

#pragma unroll
        for (int kk = 0; kk < 2; ++kk) {
            const int ko = ((kk * 4 + hi) ^ (ln & 7)) << 3;
            short8 av[4], bv[4];
#pragma unroll
            for (int fr = 0; fr < 4; ++fr)
                av[fr] = *(const short8*)&Ab[(wr * 64 + fr * 16 + ln) * 64 + ko];
#pragma unroll
            for (int fc = 0; fc < 4; ++fc)
                bv[fc] = *(const short8*)&Bb[(wc * 64 + fc * 16 + ln) * 64 + ko];
#pragma unroll
            for (int fr = 0; fr < 4; ++fr)
#pragma unroll
                for (int fc = 0; fc < 4; ++fc)
                    acc[fr][fc] = __builtin_amdgcn_mfma_f32_16x16x32_bf16(
                        av[fr], bv[fc], acc[fr][fc], 0, 0, 0);
        }
        __syncthreads();
    }

    // epilogue: per (row, this wave's 64-col group): (min, argmin, min2)
    const int grp = nblk * 2 + wc;
#pragma unroll
    for (int fr = 0; fr < 4; ++fr) {
#pragma unroll
        for (int j = 0; j < 4; ++j) {
            float m1 = INFINITY, m2 = INFINITY;
            int ix = 0;
#pragma unroll
            for (int fc = 0; fc < 4; ++fc) {
                const float d = fmaf(-2.f, acc[fr][fc][j],
                                     csq[n0 + wc * 64 + fc * 16 + ln]);
                if (d < m1) { m2 = m1; m1 = d; ix = fc * 16 + ln; }
                else        { m2 = fminf(m2, d); }
            }
#pragma unroll
            for (int off = 1; off < 16; off <<= 1) {
                const float om1 = __shfl_xor(m1, off, 64);
                const float om2 = __shfl_xor(m2, off, 64);
                const int   oix = __shfl_xor(ix, off, 64);
                if (om1 < m1) { m2 = fminf(m1, om2); m1 = om1; ix = oix; }
                else          { m2 = fminf(m2, om1); }
            }
            if (ln == 0) {
                const int row = m0 + wr * 64 + fr * 16 + hi * 4 + j;
                const unsigned lo = (bf16dn(m2) << 16) | (unsigned)ix;
                locmin64[(size_t)row * 64 + grp] =
                    ((unsigned long long)ordenc(m1) << 32) | lo;
            }
        }
    }
}

// ---- thr[row] = row min (from group minima) + DELTA (one wave per row) ----
__global__ __launch_bounds__(256) void rowthr_kernel(
        const unsigned long long* __restrict__ locmin64, float* __restrict__ thr) {
    const int row = blockIdx.x * 4 + (threadIdx.x >> 6);
    const int lane = threadIdx.x & 63;
    unsigned long long v = locmin64[(size_t)row * 64 + lane];
#pragma unroll
    for (int off = 32; off > 0; off >>= 1) {
        const unsigned long long o = __shfl_xor(v, off, 64);
        v = (o < v) ? o : v;
    }
    if (lane == 0) thr[row] = orddec((unsigned)(v >> 32)) + DELTA;
}

// ---- qualify: groups with min <= thr -> packed pairs [row:15|g:6|idx:6|full:1] ----
__global__ __launch_bounds__(256) void qualify_kernel(
    const unsigned long long* __restrict__ locmin64, const float* __restrict__ thr,
    const float* __restrict__ x, const float* __restrict__ cent,
    const float* __restrict__ csq,
    int* __restrict__ counter, int* __restrict__ list,
    unsigned long long* __restrict__ keys)
{
    const int row = blockIdx.x * 4 + (threadIdx.x >> 6);
    const int g = threadIdx.x & 63;
    const unsigned long long e = locmin64[(size_t)row * 64 + g];
    const float tf = thr[row];
    if ((unsigned)(e >> 32) <= ordenc(tf)) {
        const float m2 = bf16dec((unsigned)(e >> 16) & 0xFFFFu);
        const int idx = (int)(e & 63u);
        const int full = (m2 <= tf) ? 1 : 0;
        const int pos = atomicAdd(counter, 1);
        if (pos < PCAP) {
            list[pos] = (row << 13) | (g << 7) | (idx << 1) | full;
        } else {
            // overflow fallback (statistically dead): exact inline over group
            unsigned long long best = ~0ull;
            for (int c = 0; c < 64; ++c) {
                const int col = g * 64 + c;
                const float* xr = x + (size_t)row * DD;
                const float* cr = cent + (size_t)col * DD;
                float s = 0.f;
                for (int d = 0; d < DD; ++d) s = fmaf(xr[d], cr[d], s);
                const float dist = fmaf(-2.f, s, csq[col]);
                const unsigned long long key =
                    ((unsigned long long)ordenc(dist) << 32) | (unsigned)col;
                best = (key < best) ? key : best;
            }
            atomicMin(&keys[row], best);
        }
    }
}

// ---- rescue: wave per pair (grid-stride). single-col fast path / full-64 rare ----
__global__ __launch_bounds__(256) void rescue_kernel(
    const float* __restrict__ x, const float* __restrict__ cent,
    const float* __restrict__ csq, const int* __restrict__ counter,
    const int* __restrict__ list, unsigned long long* __restrict__ keys)
{
    int npairs = *counter;
    if (npairs > PCAP) npairs = PCAP;
    const int nwaves = gridDim.x * 4;
    const int wid = blockIdx.x * 4 + (threadIdx.x >> 6);
    const int l = threadIdx.x & 63;

    for (int p = wid; p < npairs; p += nwaves) {
        const int pair = list[p];
        const int row = pair >> 13;
        const int g = (pair >> 7) & 63;
        if (!(pair & 1)) {
            // single-col: exact fp32 dot of col = g*64 + idx
            const int col = g * 64 + ((pair >> 1) & 63);
            const float4* xr = (const float4*)(x + (size_t)row * DD);
            const float4* cr = (const float4*)(cent + (size_t)col * DD);
            const float4 a0 = xr[l * 2], a1 = xr[l * 2 + 1];
            const float4 b0 = cr[l * 2], b1 = cr[l * 2 + 1];
            float s = 0.f;
            s = fmaf(a0.x, b0.x, s); s = fmaf(a0.y, b0.y, s);
            s = fmaf(a0.z, b0.z, s); s = fmaf(a0.w, b0.w, s);
            s = fmaf(a1.x, b1.x, s); s = fmaf(a1.y, b1.y, s);
            s = fmaf(a1.z, b1.z, s); s = fmaf(a1.w, b1.w, s);
#pragma unroll
            for (int off = 1; off < 64; off <<= 1) s += __shfl_xor(s, off, 64);
            const float dist = fmaf(-2.f, s, csq[col]);
            if (l == 0) {
                const unsigned long long key =
                    ((unsigned long long)ordenc(dist) << 32) | (unsigned)col;
                atomicMin(&keys[row], key);
            }
        } else {
            // full-group: exact fp32 dists for all 64 cols (rare)
            const int cl = l >> 1, sg = l & 1;
            unsigned long long best = ~0ull;
#pragma unroll
            for (int pass = 0; pass < 2; ++pass) {
                const int col = g * 64 + pass * 32 + cl;
                const float4* xr = (const float4*)(x + (size_t)row * DD + sg * 256);
                const float4* cr = (const float4*)(cent + (size_t)col * DD + sg * 256);
                float s0 = 0.f, s1 = 0.f, s2 = 0.f, s3 = 0.f;
#pragma unroll 8
                for (int e = 0; e < 64; ++e) {
                    const float4 a = xr[e], b = cr[e];
                    s0 = fmaf(a.x, b.x, s0);
                    s1 = fmaf(a.y, b.y, s1);
                    s2 = fmaf(a.z, b.z, s2);
                    s3 = fmaf(a.w, b.w, s3);
                }
                float s = (s0 + s1) + (s2 + s3);
                s += __shfl_xor(s, 1, 64);
                const float dist = fmaf(-2.f, s, csq[col]);
                const unsigned long long key =
                    ((unsigned long long)ordenc(dist) << 32) | (unsigned)col;
                best = (key < best) ? key : best;
            }
#pragma unroll
            for (int off = 2; off < 64; off <<= 1) {
                const unsigned long long o = __shfl_xor(best, off, 64);
                best = (o < best) ? o : best;
            }
            if (l == 0) atomicMin(&keys[row], best);
        }
    }
}

__global__ __launch_bounds__(256) void finalize_kernel(
        const unsigned long long* __restrict__ keys, int* __restrict__ out) {
    const int i = blockIdx.x * 256 + threadIdx.x;
    out[i] = (int)(keys[i] & 0xFFFFFFFFull);
}

// ---------------- fallback: round-1 fp32 kernel (proven) ----------------
__global__ __launch_bounds__(256) void argmin_fp32_kernel(
        const float* __restrict__ x, const float* __restrict__ cent,
        const float* __restrict__ csq, int* __restrict__ out) {
    __shared__ float xs[16][68];
    __shared__ float cs[16][132];
    const int tid = threadIdx.x;
    const int tx = tid & 15;
    const int ty = tid >> 4;
    const int m0 = blockIdx.x * 64;
    const int srow = tid >> 2;
    const int scol = (tid & 3) << 2;
    const float* xg  = x + (size_t)(m0 + srow) * DD + scol;
    const float* cgA = cent + (size_t)srow * DD + scol;
    const float* cgB = cent + (size_t)(srow + 64) * DD + scol;
    float best[4];
    int bidx[4];
#pragma unroll
    for (int i = 0; i < 4; ++i) { best[i] = INFINITY; bidx[i] = 0; }
    for (int n0 = 0; n0 < KC; n0 += 128) {
        float acc[4][2][4];
#pragma unroll
        for (int i = 0; i < 4; ++i)
#pragma unroll
            for (int h = 0; h < 2; ++h)
#pragma unroll
                for (int j = 0; j < 4; ++j) acc[i][h][j] = 0.f;
        const size_t nOff = (size_t)n0 * DD;
        float4 rx = *(const float4*)(xg);
        float4 rc0 = *(const float4*)(cgA + nOff);
        float4 rc1 = *(const float4*)(cgB + nOff);
        for (int k0 = 0; k0 < DD; k0 += 16) {
            __syncthreads();
            const float* p = (const float*)&rx;
            xs[scol + 0][srow] = p[0]; xs[scol + 1][srow] = p[1];
            xs[scol + 2][srow] = p[2]; xs[scol + 3][srow] = p[3];
            const float* q0 = (const float*)&rc0;
            cs[scol + 0][srow] = q0[0]; cs[scol + 1][srow] = q0[1];
            cs[scol + 2][srow] = q0[2]; cs[scol + 3][srow] = q0[3];
            const float* q1 = (const float*)&rc1;
            cs[scol + 0][srow + 64] = q1[0]; cs[scol + 1][srow + 64] = q1[1];
            cs[scol + 2][srow + 64] = q1[2]; cs[scol + 3][srow + 64] = q1[3];
            __syncthreads();
            if (k0 + 16 < DD) {
                rx  = *(const float4*)(xg + k0 + 16);
                rc0 = *(const float4*)(cgA + nOff + k0 + 16);
                rc1 = *(const float4*)(cgB + nOff + k0 + 16);
            }
#pragma unroll
            for (int dd = 0; dd < 16; ++dd) {
                float4 av  = *(const float4*)&xs[dd][ty << 2];
                float4 bv0 = *(const float4*)&cs[dd][tx << 2];
                float4 bv1 = *(const float4*)&cs[dd][64 + (tx << 2)];
                const float* a  = (const float*)&av;
                const float* b0 = (const float*)&bv0;
                const float* b1 = (const float*)&bv1;
#pragma unroll
                for (int i = 0; i < 4; ++i)
#pragma unroll
                    for (int j = 0; j < 4; ++j) {
                        acc[i][0][j] = fmaf(a[i], b0[j], acc[i][0][j]);
                        acc[i][1][j] = fmaf(a[i], b1[j], acc[i][1][j]);
                    }
            }
        }
        float4 qv0 = *(const float4*)(csq + n0 + (tx << 2));
        float4 qv1 = *(const float4*)(csq + n0 + 64 + (tx << 2));
        const float* q0 = (const float*)&qv0;
        const float* q1 = (const float*)&qv1;
#pragma unroll
        for (int i = 0; i < 4; ++i)
#pragma unroll
            for (int h = 0; h < 2; ++h)
#pragma unroll
                for (int j = 0; j < 4; ++j) {
                    float qq = (h == 0) ? q0[j] : q1[j];
                    float dist = fmaf(-2.f, acc[i][h][j], qq);
                    int kk = n0 + h * 64 + (tx << 2) + j;
                    if (dist < best[i] || (dist == best[i] && kk < bidx[i])) {
                        best[i] = dist; bidx[i] = kk;
                    }
                }
    }
#pragma unroll
    for (int off = 1; off < 16; off <<= 1)
#pragma unroll
        for (int i = 0; i < 4; ++i) {
            float ov = __shfl_xor(best[i], off, 64);
            int oi = __shfl_xor(bidx[i], off, 64);
            if (ov < best[i] || (ov == best[i] && oi < bidx[i])) {
                best[i] = ov; bidx[i] = oi;
            }
        }
    if (tx == 0)
#pragma unroll
        for (int i = 0; i < 4; ++i) out[m0 + (ty << 2) + i] = bidx[i];
}

extern "C" void kernel_launch(void* const* d_in, const int* in_sizes, int n_in,
                              void* d_out, int out_size, void* d_ws, size_t ws_size,
                              hipStream_t stream) {
    const float* x    = (const float*)d_in[0];
    const float* cent = (const float*)d_in[1];
    int* out = (int*)d_out;

    const size_t xb_bytes     = (size_t)NB * DD * 2;        // 32MB
    const size_t cb_bytes     = (size_t)KC * DD * 2;        // 4MB
    const size_t locmin_bytes = (size_t)NB * 64 * 8;        // 16MB (u64)
    const size_t thr_bytes    = (size_t)NB * 4;             // 128KB
    const size_t keys_bytes   = (size_t)NB * 8;             // 256KB
    const size_t csq_bytes    = (size_t)KC * 4;             // 16KB
    const size_t cnt_bytes    = 512;
    const size_t list_bytes   = (size_t)PCAP * 4;           // 4MB
    const size_t need = xb_bytes + cb_bytes + locmin_bytes + thr_bytes +
                        keys_bytes + csq_bytes + cnt_bytes + list_bytes;

    if (ws_size >= need) {
        char* p = (char*)d_ws;
        unsigned short* xbT = (unsigned short*)p;            p += xb_bytes;
        unsigned short* cbT = (unsigned short*)p;            p += cb_bytes;
        unsigned long long* locmin64 = (unsigned long long*)p; p += locmin_bytes;
        float* thr = (float*)p;                              p += thr_bytes;
        unsigned long long* keys = (unsigned long long*)p;   p += keys_bytes;
        float* csq = (float*)p;                              p += csq_bytes;
        int* counter = (int*)p;                              p += cnt_bytes;
        int* list = (int*)p;

        hipMemsetAsync(keys, 0xFF, keys_bytes, stream);
        hipMemsetAsync(counter, 0, cnt_bytes, stream);
        tile_bf16_kernel<<<NB * DD / 8 / 256, 256, 0, stream>>>(x, xbT);
        tile_bf16_kernel<<<KC * DD / 8 / 256, 256, 0, stream>>>(cent, cbT);
        csq_kernel<<<KC / 4, 256, 0, stream>>>(cent, csq);
        gemm_min<<<(NB / 128) * (KC / 128), 256, 0, stream>>>(xbT, cbT, csq, locmin64);
        rowthr_kernel<<<NB / 4, 256, 0, stream>>>(locmin64, thr);
        qualify_kernel<<<NB / 4, 256, 0, stream>>>(locmin64, thr, x, cent, csq,
                                                   counter, list, keys);
        rescue_kernel<<<2048, 256, 0, stream>>>(x, cent, csq, counter, list, keys);
        finalize_kernel<<<NB / 256, 256, 0, stream>>>(keys, out);
    } else {
        float* csq = (float*)d_ws;
        csq_kernel<<<KC / 4, 256, 0, stream>>>(cent, csq);
        argmin_fp32_kernel<<<NB / 64, 256, 0, stream>>>(x, cent, csq, out);
    }
}

// Round 10
// 258.529 us; speedup vs baseline: 18.2806x; 2.5277x over previous
//
#include <hip/hip_runtime.h>
#include <math.h>

#define NB 32768
#define KC 4096
#define DD 512
#define DELTA 2.0f

typedef __attribute__((ext_vector_type(8))) short short8;
typedef __attribute__((ext_vector_type(4))) float facc4;

#define AS1 __attribute__((address_space(1)))
#define AS3 __attribute__((address_space(3)))

__device__ __forceinline__ void gll16(const void* g, void* lds) {
    __builtin_amdgcn_global_load_lds((const AS1 unsigned*)g, (AS3 unsigned*)lds,
                                     16, 0, 0);
}

__device__ __forceinline__ unsigned short f2bf(float f) {
    unsigned u = __float_as_uint(f);
    u += 0x7FFFu + ((u >> 16) & 1u);     // RNE
    return (unsigned short)(u >> 16);
}
__device__ __forceinline__ unsigned ordenc(float f) {
    unsigned u = __float_as_uint(f);
    return (u & 0x80000000u) ? ~u : (u | 0x80000000u);
}
__device__ __forceinline__ float orddec(unsigned o) {
    unsigned u = (o & 0x80000000u) ? (o & 0x7FFFFFFFu) : ~o;
    return __uint_as_float(u);
}
// bf16 rounded toward -inf (conservative lower bound of f)
__device__ __forceinline__ unsigned bf16dn(float f) {
    unsigned u = __float_as_uint(f);
    unsigned t = u >> 16;
    if ((u & 0xFFFFu) && (u >> 31)) t += 1;   // negative: away from zero
    return t & 0xFFFFu;
}
__device__ __forceinline__ float bf16dec(unsigned t) {
    return __uint_as_float(t << 16);
}

// ---- fp32 -> bf16 convert + tile to [blk][kstep][128 r][64 d], XOR-swizzled ----
__global__ __launch_bounds__(256) void tile_bf16_kernel(const float* __restrict__ in,
                                                        unsigned short* __restrict__ out) {
    const size_t t = (size_t)blockIdx.x * 256 + threadIdx.x;
    const int row = (int)(t >> 6);
    const int d0  = (int)(t & 63) << 3;
    const int blk = row >> 7, r = row & 127;
    const int ks  = d0 >> 6,  dw = d0 & 63;
    const int g   = dw >> 3;
    const int dws = ((g ^ (r & 7)) << 3);
    const float4* p = (const float4*)(in + (size_t)row * DD + d0);
    float4 a = p[0], b = p[1];
    unsigned q0 = (unsigned)f2bf(a.x) | ((unsigned)f2bf(a.y) << 16);
    unsigned q1 = (unsigned)f2bf(a.z) | ((unsigned)f2bf(a.w) << 16);
    unsigned q2 = (unsigned)f2bf(b.x) | ((unsigned)f2bf(b.y) << 16);
    unsigned q3 = (unsigned)f2bf(b.z) | ((unsigned)f2bf(b.w) << 16);
    const size_t o = (((size_t)blk * 8 + ks) * 128 + r) * 64 + dws;
    *(uint4*)(out + o) = make_uint4(q0, q1, q2, q3);
}

// ---------------- c_sq[k] = sum_d c[k][d]^2 (fp32) ----------------
__global__ __launch_bounds__(256) void csq_kernel(const float* __restrict__ cent,
                                                  float* __restrict__ csq) {
    const int wid  = threadIdx.x >> 6;
    const int lane = threadIdx.x & 63;
    const int k = (blockIdx.x << 2) + wid;
    const float* row = cent + (size_t)k * DD;
    float s = 0.f;
#pragma unroll
    for (int d = 0; d < DD; d += 64) {
        float v = row[d + lane];
        s = fmaf(v, v, s);
    }
#pragma unroll
    for (int off = 32; off > 0; off >>= 1) s += __shfl_xor(s, off, 64);
    if (lane == 0) csq[k] = s;
}

// ------ single-pass bf16 MFMA GEMM; locmin64[row][64]: per-64-col-group ------
// u64 = { ordenc(min):32 | bf16_down(min2):16 | pad | argmin_in_group:6 }
__global__ __launch_bounds__(256) void gemm_min(
    const unsigned short* __restrict__ xbT, const unsigned short* __restrict__ cbT,
    const float* __restrict__ csq, unsigned long long* __restrict__ locmin64)
{
    __shared__ unsigned short Ab[8192];   // 16KB
    __shared__ unsigned short Bb[8192];   // 16KB

    const int tid = threadIdx.x;
    const int l = tid & 63, w = tid >> 6;
    const int wr = w >> 1, wc = w & 1;

    const int bid = blockIdx.x;
    const int mblk = bid >> 5, nblk = bid & 31;
    const int m0 = mblk * 128, n0 = nblk * 128;

    const unsigned short* ga = xbT + (size_t)mblk * 8 * 8192 + w * 2048 + l * 8;
    const unsigned short* gb = cbT + (size_t)nblk * 8 * 8192 + w * 2048 + l * 8;

    const int hi = l >> 4, ln = l & 15;

    facc4 acc[4][4];
#pragma unroll
    for (int fr = 0; fr < 4; ++fr)
#pragma unroll
        for (int fc = 0; fc < 4; ++fc) {
            facc4 z = {0.f, 0.f, 0.f, 0.f};
            acc[fr][fc] = z;
        }

#pragma unroll 1
    for (int ks = 0; ks < 8; ++ks) {
        const unsigned short* sa = ga + (size_t)ks * 8192;
        const unsigned short* sb = gb + (size_t)ks * 8192;
#pragma unroll
        for (int q = 0; q < 4; ++q) {
            gll16(sa + q * 512, &Ab[w * 2048 + q * 512]);
            gll16(sb + q * 512, &Bb[w * 2048 + q * 512]);
        }
        __syncthreads();

#pragma unroll
        for (int kk = 0; kk < 2; ++kk) {
            const int ko = ((kk * 4 + hi) ^ (ln & 7)) << 3;
            short8 av[4], bv[4];
#pragma unroll
            for (int fr = 0; fr < 4; ++fr)
                av[fr] = *(const short8*)&Ab[(wr * 64 + fr * 16 + ln) * 64 + ko];
#pragma unroll
            for (int fc = 0; fc < 4; ++fc)
                bv[fc] = *(const short8*)&Bb[(wc * 64 + fc * 16 + ln) * 64 + ko];
#pragma unroll
            for (int fr = 0; fr < 4; ++fr)
#pragma unroll
                for (int fc = 0; fc < 4; ++fc)
                    acc[fr][fc] = __builtin_amdgcn_mfma_f32_16x16x32_bf16(
                        av[fr], bv[fc], acc[fr][fc], 0, 0, 0);
        }
        __syncthreads();
    }

    // epilogue: per (row, this wave's 64-col group): (min, argmin, min2)
    const int grp = nblk * 2 + wc;
#pragma unroll
    for (int fr = 0; fr < 4; ++fr) {
#pragma unroll
        for (int j = 0; j < 4; ++j) {
            float m1 = INFINITY, m2 = INFINITY;
            int ix = 0;
#pragma unroll
            for (int fc = 0; fc < 4; ++fc) {
                const float d = fmaf(-2.f, acc[fr][fc][j],
                                     csq[n0 + wc * 64 + fc * 16 + ln]);
                if (d < m1) { m2 = m1; m1 = d; ix = fc * 16 + ln; }
                else        { m2 = fminf(m2, d); }
            }
#pragma unroll
            for (int off = 1; off < 16; off <<= 1) {
                const float om1 = __shfl_xor(m1, off, 64);
                const float om2 = __shfl_xor(m2, off, 64);
                const int   oix = __shfl_xor(ix, off, 64);
                if (om1 < m1) { m2 = fminf(m1, om2); m1 = om1; ix = oix; }
                else          { m2 = fminf(m2, om1); }
            }
            if (ln == 0) {
                const int row = m0 + wr * 64 + fr * 16 + hi * 4 + j;
                const unsigned lo = (bf16dn(m2) << 16) | (unsigned)ix;
                locmin64[(size_t)row * 64 + grp] =
                    ((unsigned long long)ordenc(m1) << 32) | lo;
            }
        }
    }
}

// ---- fused rowthr+qualify+rescue+finalize: one wave per row, zero atomics ----
__global__ __launch_bounds__(256) void rescue_argmin_kernel(
    const float* __restrict__ x, const float* __restrict__ cent,
    const float* __restrict__ csq,
    const unsigned long long* __restrict__ locmin64, int* __restrict__ out)
{
    const int row = blockIdx.x * 4 + (threadIdx.x >> 6);
    const int l = threadIdx.x & 63;

    // lane l holds group l's entry for this row (512B coalesced read)
    const unsigned long long e = locmin64[(size_t)row * 64 + l];

    // row minimum via u64 butterfly (min value lives in high bits)
    unsigned long long v = e;
#pragma unroll
    for (int off = 32; off > 0; off >>= 1) {
        const unsigned long long o = __shfl_xor(v, off, 64);
        v = (o < v) ? o : v;
    }
    const float thr = orddec((unsigned)(v >> 32)) + DELTA;
    unsigned long long qmask = __ballot((unsigned)(e >> 32) <= ordenc(thr));

    // preload this row of x for the single-col path: lane l = dims [8l, 8l+8)
    const float4* xr = (const float4*)(x + (size_t)row * DD);
    const float4 a0 = xr[l * 2];
    const float4 a1 = xr[l * 2 + 1];

    unsigned long long best = ~0ull;
    while (qmask) {
        const int g = (int)__ffsll((long long)qmask) - 1;
        qmask &= qmask - 1;
        const unsigned long long eg = __shfl(e, g, 64);
        const float m2 = bf16dec((unsigned)(eg >> 16) & 0xFFFFu);
        if (m2 > thr) {
            // single-col: exact fp32 dot of the group's approx-argmin col
            const int col = g * 64 + (int)(eg & 63u);
            const float4* cr = (const float4*)(cent + (size_t)col * DD);
            const float4 b0 = cr[l * 2], b1 = cr[l * 2 + 1];
            float s = 0.f;
            s = fmaf(a0.x, b0.x, s); s = fmaf(a0.y, b0.y, s);
            s = fmaf(a0.z, b0.z, s); s = fmaf(a0.w, b0.w, s);
            s = fmaf(a1.x, b1.x, s); s = fmaf(a1.y, b1.y, s);
            s = fmaf(a1.z, b1.z, s); s = fmaf(a1.w, b1.w, s);
#pragma unroll
            for (int off = 1; off < 64; off <<= 1) s += __shfl_xor(s, off, 64);
            const float dist = fmaf(-2.f, s, csq[col]);
            const unsigned long long key =
                ((unsigned long long)ordenc(dist) << 32) | (unsigned)col;
            best = (key < best) ? key : best;
        } else {
            // full-group (rare): exact fp32 dists for all 64 cols
            const int cl = l >> 1, sg = l & 1;
            const float4* xh = (const float4*)(x + (size_t)row * DD + sg * 256);
            unsigned long long kb = ~0ull;
#pragma unroll
            for (int pass = 0; pass < 2; ++pass) {
                const int col = g * 64 + pass * 32 + cl;
                const float4* ch = (const float4*)(cent + (size_t)col * DD + sg * 256);
                float s0 = 0.f, s1 = 0.f, s2 = 0.f, s3 = 0.f;
#pragma unroll 8
                for (int ee = 0; ee < 64; ++ee) {
                    const float4 a = xh[ee], b = ch[ee];
                    s0 = fmaf(a.x, b.x, s0);
                    s1 = fmaf(a.y, b.y, s1);
                    s2 = fmaf(a.z, b.z, s2);
                    s3 = fmaf(a.w, b.w, s3);
                }
                float s = (s0 + s1) + (s2 + s3);
                s += __shfl_xor(s, 1, 64);      // combine the two dim-halves
                const float dist = fmaf(-2.f, s, csq[col]);
                const unsigned long long key =
                    ((unsigned long long)ordenc(dist) << 32) | (unsigned)col;
                kb = (key < kb) ? key : kb;
            }
#pragma unroll
            for (int off = 1; off < 64; off <<= 1) {
                const unsigned long long o = __shfl_xor(kb, off, 64);
                kb = (o < kb) ? o : kb;
            }
            best = (kb < best) ? kb : best;
        }
    }
    if (l == 0) out[row] = (int)(best & 0xFFFFFFFFull);
}

// ---------------- fallback: round-1 fp32 kernel (proven) ----------------
__global__ __launch_bounds__(256) void argmin_fp32_kernel(
        const float* __restrict__ x, const float* __restrict__ cent,
        const float* __restrict__ csq, int* __restrict__ out) {
    __shared__ float xs[16][68];
    __shared__ float cs[16][132];
    const int tid = threadIdx.x;
    const int tx = tid & 15;
    const int ty = tid >> 4;
    const int m0 = blockIdx.x * 64;
    const int srow = tid >> 2;
    const int scol = (tid & 3) << 2;
    const float* xg  = x + (size_t)(m0 + srow) * DD + scol;
    const float* cgA = cent + (size_t)srow * DD + scol;
    const float* cgB = cent + (size_t)(srow + 64) * DD + scol;
    float best[4];
    int bidx[4];
#pragma unroll
    for (int i = 0; i < 4; ++i) { best[i] = INFINITY; bidx[i] = 0; }
    for (int n0 = 0; n0 < KC; n0 += 128) {
        float acc[4][2][4];
#pragma unroll
        for (int i = 0; i < 4; ++i)
#pragma unroll
            for (int h = 0; h < 2; ++h)
#pragma unroll
                for (int j = 0; j < 4; ++j) acc[i][h][j] = 0.f;
        const size_t nOff = (size_t)n0 * DD;
        float4 rx = *(const float4*)(xg);
        float4 rc0 = *(const float4*)(cgA + nOff);
        float4 rc1 = *(const float4*)(cgB + nOff);
        for (int k0 = 0; k0 < DD; k0 += 16) {
            __syncthreads();
            const float* p = (const float*)&rx;
            xs[scol + 0][srow] = p[0]; xs[scol + 1][srow] = p[1];
            xs[scol + 2][srow] = p[2]; xs[scol + 3][srow] = p[3];
            const float* q0 = (const float*)&rc0;
            cs[scol + 0][srow] = q0[0]; cs[scol + 1][srow] = q0[1];
            cs[scol + 2][srow] = q0[2]; cs[scol + 3][srow] = q0[3];
            const float* q1 = (const float*)&rc1;
            cs[scol + 0][srow + 64] = q1[0]; cs[scol + 1][srow + 64] = q1[1];
            cs[scol + 2][srow + 64] = q1[2]; cs[scol + 3][srow + 64] = q1[3];
            __syncthreads();
            if (k0 + 16 < DD) {
                rx  = *(const float4*)(xg + k0 + 16);
                rc0 = *(const float4*)(cgA + nOff + k0 + 16);
                rc1 = *(const float4*)(cgB + nOff + k0 + 16);
            }
#pragma unroll
            for (int dd = 0; dd < 16; ++dd) {
                float4 av  = *(const float4*)&xs[dd][ty << 2];
                float4 bv0 = *(const float4*)&cs[dd][tx << 2];
                float4 bv1 = *(const float4*)&cs[dd][64 + (tx << 2)];
                const float* a  = (const float*)&av;
                const float* b0 = (const float*)&bv0;
                const float* b1 = (const float*)&bv1;
#pragma unroll
                for (int i = 0; i < 4; ++i)
#pragma unroll
                    for (int j = 0; j < 4; ++j) {
                        acc[i][0][j] = fmaf(a[i], b0[j], acc[i][0][j]);
                        acc[i][1][j] = fmaf(a[i], b1[j], acc[i][1][j]);
                    }
            }
        }
        float4 qv0 = *(const float4*)(csq + n0 + (tx << 2));
        float4 qv1 = *(const float4*)(csq + n0 + 64 + (tx << 2));
        const float* q0 = (const float*)&qv0;
        const float* q1 = (const float*)&qv1;
#pragma unroll
        for (int i = 0; i < 4; ++i)
#pragma unroll
            for (int h = 0; h < 2; ++h)
#pragma unroll
                for (int j = 0; j < 4; ++j) {
                    float qq = (h == 0) ? q0[j] : q1[j];
                    float dist = fmaf(-2.f, acc[i][h][j], qq);
                    int kk = n0 + h * 64 + (tx << 2) + j;
                    if (dist < best[i] || (dist == best[i] && kk < bidx[i])) {
                        best[i] = dist; bidx[i] = kk;
                    }
                }
    }
#pragma unroll
    for (int off = 1; off < 16; off <<= 1)
#pragma unroll
        for (int i = 0; i < 4; ++i) {
            float ov = __shfl_xor(best[i], off, 64);
            int oi = __shfl_xor(bidx[i], off, 64);
            if (ov < best[i] || (ov == best[i] && oi < bidx[i])) {
                best[i] = ov; bidx[i] = oi;
            }
        }
    if (tx == 0)
#pragma unroll
        for (int i = 0; i < 4; ++i) out[m0 + (ty << 2) + i] = bidx[i];
}

extern "C" void kernel_launch(void* const* d_in, const int* in_sizes, int n_in,
                              void* d_out, int out_size, void* d_ws, size_t ws_size,
                              hipStream_t stream) {
    const float* x    = (const float*)d_in[0];
    const float* cent = (const float*)d_in[1];
    int* out = (int*)d_out;

    const size_t xb_bytes     = (size_t)NB * DD * 2;        // 32MB
    const size_t cb_bytes     = (size_t)KC * DD * 2;        // 4MB
    const size_t locmin_bytes = (size_t)NB * 64 * 8;        // 16MB (u64)
    const size_t csq_bytes    = (size_t)KC * 4;             // 16KB
    const size_t need = xb_bytes + cb_bytes + locmin_bytes + csq_bytes;

    if (ws_size >= need) {
        char* p = (char*)d_ws;
        unsigned short* xbT = (unsigned short*)p;              p += xb_bytes;
        unsigned short* cbT = (unsigned short*)p;              p += cb_bytes;
        unsigned long long* locmin64 = (unsigned long long*)p; p += locmin_bytes;
        float* csq = (float*)p;

        tile_bf16_kernel<<<NB * DD / 8 / 256, 256, 0, stream>>>(x, xbT);
        tile_bf16_kernel<<<KC * DD / 8 / 256, 256, 0, stream>>>(cent, cbT);
        csq_kernel<<<KC / 4, 256, 0, stream>>>(cent, csq);
        gemm_min<<<(NB / 128) * (KC / 128), 256, 0, stream>>>(xbT, cbT, csq, locmin64);
        rescue_argmin_kernel<<<NB / 4, 256, 0, stream>>>(x, cent, csq, locmin64, out);
    } else {
        float* csq = (float*)d_ws;
        csq_kernel<<<KC / 4, 256, 0, stream>>>(cent, csq);
        argmin_fp32_kernel<<<KC == 4096 ? NB / 64 : NB / 64, 256, 0, stream>>>(
            x, cent, csq, out);
    }
}